// Round 9
// baseline (271.513 us; speedup 1.0000x reference)
//
#include <hip/hip_runtime.h>
#include <math.h>

#define NN 100000
#define MM 50000
#define EE 600000
#define DD 128
#define NB 196     // ceil(MM/256)
#define NNP 100096 // NN padded to block multiple
#define EE4 750000 // padded edge capacity: EE + 3*MM
#define SPGRID 3125 // MM/16 row-groups (exact)

typedef short bf16x8 __attribute__((ext_vector_type(8)));
typedef float f32x4 __attribute__((ext_vector_type(4)));
typedef unsigned u32x4 __attribute__((ext_vector_type(4)));

// ---- bf16 helpers (upper 16 bits of f32; RNE rounding) ----
__device__ __forceinline__ float bl(unsigned u) { return __uint_as_float(u << 16); }
__device__ __forceinline__ float bh(unsigned u) { return __uint_as_float(u & 0xFFFF0000u); }
__device__ __forceinline__ unsigned rne(float f) {
    unsigned u = __float_as_uint(f);
    return (u + 0x7FFFu + ((u >> 16) & 1u)) >> 16;
}
__device__ __forceinline__ unsigned pk2(float a, float b) { return rne(a) | (rne(b) << 16); }

// a[0..7] += v * bf16x8(u)   (spmm inner op)
__device__ __forceinline__ void fmab8(float v, uint4 u, float* a) {
    a[0] = fmaf(v, bl(u.x), a[0]); a[1] = fmaf(v, bh(u.x), a[1]);
    a[2] = fmaf(v, bl(u.y), a[2]); a[3] = fmaf(v, bh(u.y), a[3]);
    a[4] = fmaf(v, bl(u.z), a[4]); a[5] = fmaf(v, bh(u.z), a[5]);
    a[6] = fmaf(v, bl(u.w), a[6]); a[7] = fmaf(v, bh(u.w), a[7]);
}

__device__ __forceinline__ void fma21(float h, const float* wrow, float* a) {
    #pragma unroll
    for (int j = 0; j < 21; ++j) a[j] = fmaf(h, wrow[j], a[j]);
}

// --- K1 front: X0 = row-major bf16 of feat[index] (float4 reads),
//     invidx1[index[i]] = i+1 (0-default via memset), edge degree+slot atomics,
//     packed transposed weights. Grid = MM*32 threads exactly. ---
__global__ __launch_bounds__(256) void front_kernel(
    const int* __restrict__ erow, const float* __restrict__ eval,
    unsigned long long* __restrict__ dcpack, int* __restrict__ slot,
    const float* __restrict__ feat, const int* __restrict__ index,
    int* __restrict__ invidx1, unsigned* __restrict__ X0,
    const float* __restrict__ W1, const float* __restrict__ W2,
    unsigned* __restrict__ W1b, unsigned* __restrict__ W2b) {
    int i = blockIdx.x * 256 + threadIdx.x;   // grid = MM*32 exactly
    int n = i >> 5, u = i & 31;
    {   // X0 row-major [MM][64 dwords]; thread writes dwords 2u, 2u+1
        int idx = index[n];
        float4 f = ((const float4*)feat)[(size_t)idx * 32 + u];
        unsigned* dst = X0 + (size_t)n * 64 + 2 * u;
        dst[0] = pk2(f.x, f.y);
        dst[1] = pk2(f.z, f.w);
    }
    if (i < MM) invidx1[index[i]] = i + 1;
    if (i < 4096) {          // W1^T: [j=0..63][kp=0..63]  (K=128)
        int j = i >> 6, kp = i & 63;
        W1b[i] = pk2(W1[(2 * kp) * 64 + j], W1[(2 * kp + 1) * 64 + j]);
    } else if (i < 5120) {   // W2^T: [j=0..31][kp=0..31]
        int t = i - 4096;
        int j = t >> 5, kp = t & 31;
        W2b[t] = pk2(W2[(2 * kp) * 32 + j], W2[(2 * kp + 1) * 32 + j]);
    }
    if (i < EE) {
        int r = erow[i];
        unsigned long long add = (1ULL << 44) | (unsigned long long)(eval[i] * 4294967296.0f);
        unsigned long long old = atomicAdd(&dcpack[r], add);
        slot[i] = (int)(old >> 44);
    }
}

// --- unpack deg/cnt; dis; per-block degree histogram ---
__global__ void setup_kernel(const unsigned long long* __restrict__ dcpack,
                             float* __restrict__ dis, int* __restrict__ cnt,
                             int* __restrict__ blockhist) {
    __shared__ int lh[256];
    int tid = threadIdx.x;
    int i = blockIdx.x * 256 + tid;
    lh[tid] = 0;
    __syncthreads();
    if (i < MM) {
        unsigned long long pkv = dcpack[i];
        int v = (int)(pkv >> 44);
        float dsum = (float)(pkv & ((1ULL << 44) - 1)) * (1.0f / 4294967296.0f);
        dis[i] = rsqrtf(dsum + 1e-8f);
        cnt[i] = v;
        atomicAdd(&lh[min(v, 255)], 1);
    }
    __syncthreads();
    blockhist[tid * NB + blockIdx.x] = lh[tid];   // [deg][block]
}

// --- per-degree exclusive scan across blocks; one block per degree bin ---
__global__ void scan_kernel(const int* __restrict__ blockhist,
                            int* __restrict__ blockoff, int* __restrict__ total) {
    int d = blockIdx.x;       // 256 bins
    int lane = threadIdx.x;   // 64 threads
    int carry = 0;
    for (int base = 0; base < NB; base += 64) {
        int b = base + lane;
        int v = (b < NB) ? blockhist[d * NB + b] : 0;
        int x = v;
        #pragma unroll
        for (int off = 1; off < 64; off <<= 1) {
            int t = __shfl_up(x, off, 64);
            if (lane >= off) x += t;
        }
        if (b < NB) blockoff[d * NB + b] = carry + x - v;
        carry += __shfl(x, 63);
    }
    if (lane == 0) total[d] = carry;
}

// --- counting-sort finalize: meta/row_s4 + int2 zero pads ---
__global__ void sort_kernel(const int* __restrict__ cnt, const int* __restrict__ blockoff,
                            const int* __restrict__ total,
                            int4* __restrict__ meta, int* __restrict__ row_s4,
                            int2* __restrict__ cv_s) {
    __shared__ int lh[256], sbin[256], spad[256], ws[8];
    int tid = threadIdx.x, lane = tid & 63, w = tid >> 6;
    lh[tid] = 0;
    int t = total[tid];
    int v1 = t, v2 = t * ((tid + 3) & ~3);   // rows in bin; padded edges in bin
    int x1 = v1, x2 = v2;
    #pragma unroll
    for (int off = 1; off < 64; off <<= 1) {
        int t1 = __shfl_up(x1, off, 64);
        int t2 = __shfl_up(x2, off, 64);
        if (lane >= off) { x1 += t1; x2 += t2; }
    }
    if (lane == 63) { ws[w] = x1; ws[4 + w] = x2; }
    __syncthreads();
    int a1 = 0, a2 = 0;
    for (int q = 0; q < w; ++q) { a1 += ws[q]; a2 += ws[4 + q]; }
    sbin[tid] = a1 + x1 - v1;   // exclusive: first sorted pos of bin
    spad[tid] = a2 + x2 - v2;   // exclusive: first padded edge slot of bin
    __syncthreads();
    int i = blockIdx.x * 256 + tid;
    if (i < MM) {
        int d = cnt[i], c = min(d, 255);
        int lrank = atomicAdd(&lh[c], 1);
        int k = blockoff[c * NB + blockIdx.x] + lrank;  // global rank within bin
        int spos = sbin[c] + k;
        int s4 = spad[c] + k * ((d + 3) & ~3);
        // store descending by degree so heavy rows are scheduled first
        meta[MM - 1 - spos] = make_int4(s4, d, i, 0);
        row_s4[i] = s4;
        int p4 = (d + 3) & ~3;                 // write the <=3 tail pads
        for (int pp = d; pp < p4; ++pp) cv_s[s4 + pp] = make_int2(0, 0);
    }
}

// --- bucket edges into padded sorted CSR; ONE int2 store per edge ---
__global__ void scatter_kernel(const int* __restrict__ row, const int* __restrict__ col,
                               const float* __restrict__ val, const float* __restrict__ dis,
                               const int* __restrict__ row_s4, const int* __restrict__ slot,
                               int2* __restrict__ cv_s) {
    int e = blockIdx.x * 256 + threadIdx.x;
    if (e < EE) {
        int r = row[e], c = col[e];
        int pos = row_s4[r] + slot[e];
        cv_s[pos] = make_int2(c, __float_as_int(val[e] * dis[r] * dis[c]));
    }
}

// --- SpMM: 16-lane group per degree-sorted row, 4 groups/wave, 3125 blocks,
//     __launch_bounds__(256,8) pins full occupancy (32 waves/CU).
//     TWO-DEEP software pipeline: gathers for batch b+1 issue BEFORE batch b's
//     FMAs, and batch b+2's CV pair prefetches in the same iteration ->
//     8 gathers + 2 CV outstanding per thread (vs 4+2).
//     nb = CEIL(d/4): final partial batch covered by zero-pads (r8 bug fixed).
//     FMA order per row unchanged -> bit-identical to r7. ---
__global__ __launch_bounds__(256, 8) void spmm_kernel(
    const int4* __restrict__ meta, const int2* __restrict__ cv,
    const unsigned short* __restrict__ X, unsigned short* __restrict__ Y) {
    int lane = threadIdx.x & 63, wid = threadIdx.x >> 6;
    int g = lane >> 4, sub = lane & 15;
    int ri = blockIdx.x * 16 + wid * 4 + g;   // MM%16==0 -> always < MM
    int4 mt = meta[ri];                       // {s4, deg, row, -}
    int s = mt.x, d = mt.y;
    const uint4* __restrict__ X4 = (const uint4*)X;
    const u32x4* __restrict__ CV = (const u32x4*)cv;   // 2 edges per u32x4
    float a[8] = {0.f, 0.f, 0.f, 0.f, 0.f, 0.f, 0.f, 0.f};
    int nb = (d + 3) >> 2;                    // CEIL: pads fill the last batch
    int cb = s >> 1;                          // u32x4 index of batch 0
    uint4 g0, g1, g2, g3;                     // current batch gathers (in flight)
    float v0, v1, v2, v3;                     // current batch values
    u32x4 q0, q1;                             // prefetched CV of NEXT batch
    if (nb > 0) {
        u32x4 c0 = CV[cb], c1 = CV[cb + 1];
        g0 = X4[(int)c0.x * 16 + sub]; g1 = X4[(int)c0.z * 16 + sub];
        g2 = X4[(int)c1.x * 16 + sub]; g3 = X4[(int)c1.z * 16 + sub];
        v0 = __uint_as_float(c0.y); v1 = __uint_as_float(c0.w);
        v2 = __uint_as_float(c1.y); v3 = __uint_as_float(c1.w);
        if (nb > 1) { q0 = CV[cb + 2]; q1 = CV[cb + 3]; }
    }
    for (int b = 1; b < nb; ++b) {
        // issue batch b's gathers (CV was prefetched last iteration)
        uint4 h0 = X4[(int)q0.x * 16 + sub], h1 = X4[(int)q0.z * 16 + sub];
        uint4 h2 = X4[(int)q1.x * 16 + sub], h3 = X4[(int)q1.z * 16 + sub];
        float w0 = __uint_as_float(q0.y), w1 = __uint_as_float(q0.w);
        float w2 = __uint_as_float(q1.y), w3 = __uint_as_float(q1.w);
        // prefetch batch b+1's CV
        if (b + 1 < nb) { int o = cb + 2 * (b + 1); q0 = CV[o]; q1 = CV[o + 1]; }
        // consume batch b-1 (gathers had a full iteration in flight)
        fmab8(v0, g0, a); fmab8(v1, g1, a); fmab8(v2, g2, a); fmab8(v3, g3, a);
        g0 = h0; g1 = h1; g2 = h2; g3 = h3;
        v0 = w0; v1 = w1; v2 = w2; v3 = w3;
    }
    if (nb > 0) {
        fmab8(v0, g0, a); fmab8(v1, g1, a); fmab8(v2, g2, a); fmab8(v3, g3, a);
    }
    uint4 o;
    o.x = pk2(a[0], a[1]); o.y = pk2(a[2], a[3]);
    o.z = pk2(a[4], a[5]); o.w = pk2(a[6], a[7]);
    ((uint4*)Y)[mt.z * 16 + sub] = o;
}

// --- MFMA MLP: 64 nodes/block (4 waves x 16 nodes), BARRIER-FREE.
//     A-frags per node: invidx1[n]>0 -> row-major Xc row (bf16, spmm L3 output);
//     else -> feat row f32, packed to bf16 in-register (same rne => bit-identical). ---
__global__ __launch_bounds__(256) void mlp_kernel(
    const unsigned* __restrict__ Xc, const float* __restrict__ feat,
    const int* __restrict__ invidx1,
    const unsigned* __restrict__ W1b, const float* __restrict__ b1,
    const unsigned* __restrict__ W2b, const float* __restrict__ b2,
    const float* __restrict__ W3, const float* __restrict__ b3,
    const float* __restrict__ W4, float* __restrict__ out) {
    __shared__ float hls[4 * 1088];   // per-wave 16x68-f32 region
    int tid = threadIdx.x;
    int lane = tid & 63, w = tid >> 6;
    int p = lane & 15, q = lane >> 4;
    float* hw = hls + w * 1088;
    int nb = blockIdx.x * 64;
    int node = nb + w * 16 + p;
    int nc = min(node, NN - 1);       // clamp tail (output write is guarded)
    int iv = invidx1[nc];

    // ---- L1: A from Xc (row-major) or feat (f32 pack), B direct from W1b ----
    bf16x8 af[4];
    if (iv > 0) {
        int r = iv - 1;
        #pragma unroll
        for (int kc = 0; kc < 4; ++kc) {
            uint4 u = *(const uint4*)(Xc + (size_t)r * 64 + kc * 16 + q * 4);
            af[kc] = *(const bf16x8*)&u;
        }
    } else {
        const float4* F = (const float4*)feat;
        #pragma unroll
        for (int kc = 0; kc < 4; ++kc) {
            float4 f0 = F[(size_t)nc * 32 + kc * 8 + q * 2];
            float4 f1 = F[(size_t)nc * 32 + kc * 8 + q * 2 + 1];
            uint4 uu = make_uint4(pk2(f0.x, f0.y), pk2(f0.z, f0.w),
                                  pk2(f1.x, f1.y), pk2(f1.z, f1.w));
            af[kc] = *(const bf16x8*)&uu;
        }
    }
    f32x4 acc[4];
    #pragma unroll
    for (int jt = 0; jt < 4; ++jt) {
        float bv = b1[jt * 16 + p];
        acc[jt][0] = bv; acc[jt][1] = bv; acc[jt][2] = bv; acc[jt][3] = bv;
    }
    #pragma unroll
    for (int jt = 0; jt < 4; ++jt) {
        #pragma unroll
        for (int kc = 0; kc < 4; ++kc) {
            uint4 u = *(const uint4*)(W1b + (jt * 16 + p) * 64 + kc * 16 + q * 4);
            bf16x8 bf = *(const bf16x8*)&u;
            acc[jt] = __builtin_amdgcn_mfma_f32_16x16x32_bf16(af[kc], bf, acc[jt], 0, 0, 0);
        }
    }
    // h1 -> wave-private LDS (C layout: node=q*4+r, col=jt*16+p); leaky ReLU
    #pragma unroll
    for (int jt = 0; jt < 4; ++jt) {
        #pragma unroll
        for (int r = 0; r < 4; ++r) {
            float v = acc[jt][r];
            v = v > 0.f ? v : 0.01f * v;
            hw[(q * 4 + r) * 68 + jt * 16 + p] = v;
        }
    }
    // ---- L2: A from hw (pack f32->bf16), B direct from W2b ----
    bf16x8 a2f[2];
    #pragma unroll
    for (int kc = 0; kc < 2; ++kc) {
        const float* hp = hw + p * 68 + kc * 32 + q * 8;
        f32x4 v0 = *(const f32x4*)hp;
        f32x4 v1 = *(const f32x4*)(hp + 4);
        uint4 uu = make_uint4(pk2(v0[0], v0[1]), pk2(v0[2], v0[3]),
                              pk2(v1[0], v1[1]), pk2(v1[2], v1[3]));
        a2f[kc] = *(const bf16x8*)&uu;
    }
    f32x4 acc2[2];
    #pragma unroll
    for (int jt = 0; jt < 2; ++jt) {
        float bv = b2[jt * 16 + p];
        acc2[jt][0] = bv; acc2[jt][1] = bv; acc2[jt][2] = bv; acc2[jt][3] = bv;
        #pragma unroll
        for (int kc = 0; kc < 2; ++kc) {
            uint4 u = *(const uint4*)(W2b + (jt * 16 + p) * 32 + kc * 16 + q * 4);
            bf16x8 bf = *(const bf16x8*)&u;
            acc2[jt] = __builtin_amdgcn_mfma_f32_16x16x32_bf16(a2f[kc], bf, acc2[jt], 0, 0, 0);
        }
    }
    // h2 -> same wave-private LDS (all h1 reads by this wave precede, in-order LDS)
    #pragma unroll
    for (int jt = 0; jt < 2; ++jt) {
        #pragma unroll
        for (int r = 0; r < 4; ++r) {
            float v = acc2[jt][r];
            v = v > 0.f ? v : 0.01f * v;
            hw[(q * 4 + r) * 36 + jt * 16 + p] = v;
        }
    }
    // ---- L3+L4 scalar tail (q-groups redundant; W3/W4 via s_load) ----
    float a3[21];
    #pragma unroll
    for (int j = 0; j < 21; ++j) a3[j] = b3[j];
    #pragma unroll 4
    for (int k = 0; k < 32; ++k) {
        float hk = hw[p * 36 + k];
        fma21(hk, W3 + k * 21, a3);
    }
    float s = 0.f;
    #pragma unroll
    for (int j = 0; j < 21; ++j) {
        float vj = a3[j] > 0.f ? a3[j] : 0.01f * a3[j];
        s = fmaf(vj, W4[j], s);
    }
    if (q == 0) {
        if (node < NN) out[node] = 1.f / (1.f + expf(-s));
    }
}

extern "C" void kernel_launch(void* const* d_in, const int* in_sizes, int n_in,
                              void* d_out, int out_size, void* d_ws, size_t ws_size,
                              hipStream_t stream) {
    const float* feat = (const float*)d_in[0];
    const int*   index = (const int*)d_in[1];
    const int*   erow = (const int*)d_in[2];
    const int*   ecol = (const int*)d_in[3];
    const float* evalp = (const float*)d_in[4];
    const float* W1 = (const float*)d_in[5];
    const float* b1 = (const float*)d_in[6];
    const float* W2 = (const float*)d_in[7];
    const float* b2 = (const float*)d_in[8];
    const float* W3 = (const float*)d_in[9];
    const float* b3 = (const float*)d_in[10];
    const float* W4 = (const float*)d_in[11];
    float* out = (float*)d_out;

    char* ws = (char*)d_ws;
    size_t off = 0;
    auto alloc = [&](size_t bytes) -> void* {
        void* p = ws + off;
        off += (bytes + 255) & ~(size_t)255;
        return p;
    };
    // dcpack + invidx1 contiguous: ONE zeroing memset covers both
    unsigned long long* dcpack = (unsigned long long*)alloc((size_t)MM * 8);
    int*   invidx1 = (int*)  alloc((size_t)NN * 4);
    size_t zero_span = (size_t)((char*)invidx1 - (char*)dcpack) + (size_t)NN * 4;

    int2*  cv_s    = (int2*) alloc((size_t)EE4 * 8);
    float* dis     = (float*)alloc((size_t)MM * 4);
    int*   cnt     = (int*)  alloc((size_t)MM * 4);
    int*   slot    = (int*)  alloc((size_t)EE * 4);
    int*   row_s4  = (int*)  alloc((size_t)MM * 4);
    int*   blockhist = (int*)alloc((size_t)256 * NB * 4);
    int*   blockoff  = (int*)alloc((size_t)256 * NB * 4);
    int*   total     = (int*)alloc((size_t)256 * 4);
    int4*  meta      = (int4*)alloc((size_t)MM * 16);
    unsigned* W1b  = (unsigned*)alloc(4096 * 4);
    unsigned* W2b  = (unsigned*)alloc(1024 * 4);
    unsigned* X0   = (unsigned*)alloc((size_t)MM * DD * 2);  // row-major [MM][64 dwords]
    unsigned* Xa   = (unsigned*)alloc((size_t)MM * DD * 2);
    unsigned* Xb   = (unsigned*)alloc((size_t)MM * DD * 2);
    unsigned* Xc   = (unsigned*)alloc((size_t)MM * DD * 2);

    (void)hipMemsetAsync(dcpack, 0, zero_span, stream);

    front_kernel<<<(MM * 32) / 256, 256, 0, stream>>>(
        erow, evalp, dcpack, slot, feat, index, invidx1, X0, W1, W2, W1b, W2b);
    setup_kernel<<<NB, 256, 0, stream>>>(dcpack, dis, cnt, blockhist);
    scan_kernel<<<256, 64, 0, stream>>>(blockhist, blockoff, total);
    sort_kernel<<<NB, 256, 0, stream>>>(cnt, blockoff, total, meta, row_s4, cv_s);
    scatter_kernel<<<(EE + 255) / 256, 256, 0, stream>>>(erow, ecol, evalp, dis,
                                                         row_s4, slot, cv_s);

    spmm_kernel<<<SPGRID, 256, 0, stream>>>(meta, cv_s,
                                            (const unsigned short*)X0, (unsigned short*)Xa);
    spmm_kernel<<<SPGRID, 256, 0, stream>>>(meta, cv_s,
                                            (const unsigned short*)Xa, (unsigned short*)Xb);
    spmm_kernel<<<SPGRID, 256, 0, stream>>>(meta, cv_s,
                                            (const unsigned short*)Xb, (unsigned short*)Xc);

    mlp_kernel<<<(NNP + 63) / 64, 256, 0, stream>>>(Xc, feat, invidx1,
                                                    W1b, b1, W2b, b2,
                                                    W3, b3, W4, out);
}

// Round 10
// 243.381 us; speedup vs baseline: 1.1156x; 1.1156x over previous
//
#include <hip/hip_runtime.h>
#include <math.h>

#define NN 100000
#define MM 50000
#define EE 600000
#define DD 128
#define NB 196     // ceil(MM/256)
#define NNP 100096 // NN padded to block multiple
#define EE4 750000 // padded edge capacity: EE + 3*MM
#define SPGRID 3125 // MM/16 row-groups (exact)

typedef short bf16x8 __attribute__((ext_vector_type(8)));
typedef float f32x4 __attribute__((ext_vector_type(4)));
typedef unsigned u32x4 __attribute__((ext_vector_type(4)));

// ---- bf16 helpers (upper 16 bits of f32; RNE rounding) ----
__device__ __forceinline__ float bl(unsigned u) { return __uint_as_float(u << 16); }
__device__ __forceinline__ float bh(unsigned u) { return __uint_as_float(u & 0xFFFF0000u); }
__device__ __forceinline__ unsigned rne(float f) {
    unsigned u = __float_as_uint(f);
    return (u + 0x7FFFu + ((u >> 16) & 1u)) >> 16;
}
__device__ __forceinline__ unsigned pk2(float a, float b) { return rne(a) | (rne(b) << 16); }

// a[0..7] += v * bf16x8(u)   (spmm inner op)
__device__ __forceinline__ void fmab8(float v, uint4 u, float* a) {
    a[0] = fmaf(v, bl(u.x), a[0]); a[1] = fmaf(v, bh(u.x), a[1]);
    a[2] = fmaf(v, bl(u.y), a[2]); a[3] = fmaf(v, bh(u.y), a[3]);
    a[4] = fmaf(v, bl(u.z), a[4]); a[5] = fmaf(v, bh(u.z), a[5]);
    a[6] = fmaf(v, bl(u.w), a[6]); a[7] = fmaf(v, bh(u.w), a[7]);
}

__device__ __forceinline__ void fma21(float h, const float* wrow, float* a) {
    #pragma unroll
    for (int j = 0; j < 21; ++j) a[j] = fmaf(h, wrow[j], a[j]);
}

// --- K1 front: atomic ISSUED FIRST, slot stored LAST -> the atomic's return
//     latency hides under the independent streaming work (X0 convert, weights).
//     X0 = row-major bf16 of feat[index]; invidx1[index[i]] = i+1. ---
__global__ __launch_bounds__(256) void front_kernel(
    const int* __restrict__ erow, const float* __restrict__ eval,
    unsigned long long* __restrict__ dcpack, int* __restrict__ slot,
    const float* __restrict__ feat, const int* __restrict__ index,
    int* __restrict__ invidx1, unsigned* __restrict__ X0,
    const float* __restrict__ W1, const float* __restrict__ W2,
    unsigned* __restrict__ W1b, unsigned* __restrict__ W2b) {
    int i = blockIdx.x * 256 + threadIdx.x;   // grid = MM*32 exactly
    int n = i >> 5, u = i & 31;
    // ---- issue the returning atomic EARLY ----
    bool edge = (i < EE);
    unsigned long long old = 0;
    if (edge) {
        int r = erow[i];
        unsigned long long add = (1ULL << 44) | (unsigned long long)(eval[i] * 4294967296.0f);
        old = atomicAdd(&dcpack[r], add);
    }
    // ---- independent streaming work overlaps the atomic's return ----
    {   // X0 row-major [MM][64 dwords]; thread writes dwords 2u, 2u+1
        int idx = index[n];
        float4 f = ((const float4*)feat)[(size_t)idx * 32 + u];
        unsigned* dst = X0 + (size_t)n * 64 + 2 * u;
        dst[0] = pk2(f.x, f.y);
        dst[1] = pk2(f.z, f.w);
    }
    if (i < MM) invidx1[index[i]] = i + 1;
    if (i < 4096) {          // W1^T: [j=0..63][kp=0..63]  (K=128)
        int j = i >> 6, kp = i & 63;
        W1b[i] = pk2(W1[(2 * kp) * 64 + j], W1[(2 * kp + 1) * 64 + j]);
    } else if (i < 5120) {   // W2^T: [j=0..31][kp=0..31]
        int t = i - 4096;
        int j = t >> 5, kp = t & 31;
        W2b[t] = pk2(W2[(2 * kp) * 32 + j], W2[(2 * kp + 1) * 32 + j]);
    }
    // ---- consume the atomic result LAST ----
    if (edge) slot[i] = (int)(old >> 44);
}

// --- unpack deg/cnt; dis; per-block degree histogram ---
__global__ void setup_kernel(const unsigned long long* __restrict__ dcpack,
                             float* __restrict__ dis, int* __restrict__ cnt,
                             int* __restrict__ blockhist) {
    __shared__ int lh[256];
    int tid = threadIdx.x;
    int i = blockIdx.x * 256 + tid;
    lh[tid] = 0;
    __syncthreads();
    if (i < MM) {
        unsigned long long pkv = dcpack[i];
        int v = (int)(pkv >> 44);
        float dsum = (float)(pkv & ((1ULL << 44) - 1)) * (1.0f / 4294967296.0f);
        dis[i] = rsqrtf(dsum + 1e-8f);
        cnt[i] = v;
        atomicAdd(&lh[min(v, 255)], 1);
    }
    __syncthreads();
    blockhist[tid * NB + blockIdx.x] = lh[tid];   // [deg][block]
}

// --- per-degree exclusive scan across blocks; one block per degree bin ---
__global__ void scan_kernel(const int* __restrict__ blockhist,
                            int* __restrict__ blockoff, int* __restrict__ total) {
    int d = blockIdx.x;       // 256 bins
    int lane = threadIdx.x;   // 64 threads
    int carry = 0;
    for (int base = 0; base < NB; base += 64) {
        int b = base + lane;
        int v = (b < NB) ? blockhist[d * NB + b] : 0;
        int x = v;
        #pragma unroll
        for (int off = 1; off < 64; off <<= 1) {
            int t = __shfl_up(x, off, 64);
            if (lane >= off) x += t;
        }
        if (b < NB) blockoff[d * NB + b] = carry + x - v;
        carry += __shfl(x, 63);
    }
    if (lane == 0) total[d] = carry;
}

// --- counting-sort finalize: meta/row_s4 + int2 zero pads ---
__global__ void sort_kernel(const int* __restrict__ cnt, const int* __restrict__ blockoff,
                            const int* __restrict__ total,
                            int4* __restrict__ meta, int* __restrict__ row_s4,
                            int2* __restrict__ cv_s) {
    __shared__ int lh[256], sbin[256], spad[256], ws[8];
    int tid = threadIdx.x, lane = tid & 63, w = tid >> 6;
    lh[tid] = 0;
    int t = total[tid];
    int v1 = t, v2 = t * ((tid + 3) & ~3);   // rows in bin; padded edges in bin
    int x1 = v1, x2 = v2;
    #pragma unroll
    for (int off = 1; off < 64; off <<= 1) {
        int t1 = __shfl_up(x1, off, 64);
        int t2 = __shfl_up(x2, off, 64);
        if (lane >= off) { x1 += t1; x2 += t2; }
    }
    if (lane == 63) { ws[w] = x1; ws[4 + w] = x2; }
    __syncthreads();
    int a1 = 0, a2 = 0;
    for (int q = 0; q < w; ++q) { a1 += ws[q]; a2 += ws[4 + q]; }
    sbin[tid] = a1 + x1 - v1;   // exclusive: first sorted pos of bin
    spad[tid] = a2 + x2 - v2;   // exclusive: first padded edge slot of bin
    __syncthreads();
    int i = blockIdx.x * 256 + tid;
    if (i < MM) {
        int d = cnt[i], c = min(d, 255);
        int lrank = atomicAdd(&lh[c], 1);
        int k = blockoff[c * NB + blockIdx.x] + lrank;  // global rank within bin
        int spos = sbin[c] + k;
        int s4 = spad[c] + k * ((d + 3) & ~3);
        // store descending by degree so heavy rows are scheduled first
        meta[MM - 1 - spos] = make_int4(s4, d, i, 0);
        row_s4[i] = s4;
        int p4 = (d + 3) & ~3;                 // write the <=3 tail pads
        for (int pp = d; pp < p4; ++pp) cv_s[s4 + pp] = make_int2(0, 0);
    }
}

// --- bucket edges into padded sorted CSR; ONE int2 store per edge ---
__global__ void scatter_kernel(const int* __restrict__ row, const int* __restrict__ col,
                               const float* __restrict__ val, const float* __restrict__ dis,
                               const int* __restrict__ row_s4, const int* __restrict__ slot,
                               int2* __restrict__ cv_s) {
    int e = blockIdx.x * 256 + threadIdx.x;
    if (e < EE) {
        int r = row[e], c = col[e];
        int pos = row_s4[r] + slot[e];
        cv_s[pos] = make_int2(c, __float_as_int(val[e] * dis[r] * dis[c]));
    }
}

// --- SpMM (r7 form — best measured): 16-lane group per degree-sorted row,
//     4 groups/wave, 3125 blocks, full occupancy. Branchless pad4 loop;
//     CV software-pipelined one batch ahead. ---
__global__ __launch_bounds__(256) void spmm_kernel(
    const int4* __restrict__ meta, const int2* __restrict__ cv,
    const unsigned short* __restrict__ X, unsigned short* __restrict__ Y) {
    int lane = threadIdx.x & 63, wid = threadIdx.x >> 6;
    int g = lane >> 4, sub = lane & 15;
    int ri = blockIdx.x * 16 + wid * 4 + g;   // MM%16==0 -> always < MM
    int4 mt = meta[ri];                       // {s4, deg, row, -}
    int s = mt.x, d = mt.y;
    const uint4* __restrict__ X4 = (const uint4*)X;
    const u32x4* __restrict__ CV = (const u32x4*)cv;   // 2 edges per u32x4
    float a[8] = {0.f, 0.f, 0.f, 0.f, 0.f, 0.f, 0.f, 0.f};
    int e4 = s + d;
    u32x4 p0, p1;
    if (d > 0) { p0 = CV[s >> 1]; p1 = CV[(s >> 1) + 1]; }
    for (int base = s; base < e4; base += 4) {
        u32x4 q0 = p0, q1 = p1;
        int nxt = (base + 4) >> 1;
        if (base + 4 < e4) { p0 = CV[nxt]; p1 = CV[nxt + 1]; }  // prefetch next batch
        uint4 u0 = X4[(int)q0.x * 16 + sub];
        uint4 u1 = X4[(int)q0.z * 16 + sub];
        uint4 u2 = X4[(int)q1.x * 16 + sub];
        uint4 u3 = X4[(int)q1.z * 16 + sub];
        fmab8(__uint_as_float(q0.y), u0, a);
        fmab8(__uint_as_float(q0.w), u1, a);
        fmab8(__uint_as_float(q1.y), u2, a);
        fmab8(__uint_as_float(q1.w), u3, a);
    }
    uint4 o;
    o.x = pk2(a[0], a[1]); o.y = pk2(a[2], a[3]);
    o.z = pk2(a[4], a[5]); o.w = pk2(a[6], a[7]);
    ((uint4*)Y)[mt.z * 16 + sub] = o;
}

// --- MFMA MLP: 64 nodes/block (4 waves x 16 nodes), BARRIER-FREE.
//     A-frags per node: invidx1[n]>0 -> row-major Xc row (bf16, spmm L3 output);
//     else -> feat row f32, packed to bf16 in-register (same rne => bit-identical). ---
__global__ __launch_bounds__(256) void mlp_kernel(
    const unsigned* __restrict__ Xc, const float* __restrict__ feat,
    const int* __restrict__ invidx1,
    const unsigned* __restrict__ W1b, const float* __restrict__ b1,
    const unsigned* __restrict__ W2b, const float* __restrict__ b2,
    const float* __restrict__ W3, const float* __restrict__ b3,
    const float* __restrict__ W4, float* __restrict__ out) {
    __shared__ float hls[4 * 1088];   // per-wave 16x68-f32 region
    int tid = threadIdx.x;
    int lane = tid & 63, w = tid >> 6;
    int p = lane & 15, q = lane >> 4;
    float* hw = hls + w * 1088;
    int nb = blockIdx.x * 64;
    int node = nb + w * 16 + p;
    int nc = min(node, NN - 1);       // clamp tail (output write is guarded)
    int iv = invidx1[nc];

    // ---- L1: A from Xc (row-major) or feat (f32 pack), B direct from W1b ----
    bf16x8 af[4];
    if (iv > 0) {
        int r = iv - 1;
        #pragma unroll
        for (int kc = 0; kc < 4; ++kc) {
            uint4 u = *(const uint4*)(Xc + (size_t)r * 64 + kc * 16 + q * 4);
            af[kc] = *(const bf16x8*)&u;
        }
    } else {
        const float4* F = (const float4*)feat;
        #pragma unroll
        for (int kc = 0; kc < 4; ++kc) {
            float4 f0 = F[(size_t)nc * 32 + kc * 8 + q * 2];
            float4 f1 = F[(size_t)nc * 32 + kc * 8 + q * 2 + 1];
            uint4 uu = make_uint4(pk2(f0.x, f0.y), pk2(f0.z, f0.w),
                                  pk2(f1.x, f1.y), pk2(f1.z, f1.w));
            af[kc] = *(const bf16x8*)&uu;
        }
    }
    f32x4 acc[4];
    #pragma unroll
    for (int jt = 0; jt < 4; ++jt) {
        float bv = b1[jt * 16 + p];
        acc[jt][0] = bv; acc[jt][1] = bv; acc[jt][2] = bv; acc[jt][3] = bv;
    }
    #pragma unroll
    for (int jt = 0; jt < 4; ++jt) {
        #pragma unroll
        for (int kc = 0; kc < 4; ++kc) {
            uint4 u = *(const uint4*)(W1b + (jt * 16 + p) * 64 + kc * 16 + q * 4);
            bf16x8 bf = *(const bf16x8*)&u;
            acc[jt] = __builtin_amdgcn_mfma_f32_16x16x32_bf16(af[kc], bf, acc[jt], 0, 0, 0);
        }
    }
    // h1 -> wave-private LDS (C layout: node=q*4+r, col=jt*16+p); leaky ReLU
    #pragma unroll
    for (int jt = 0; jt < 4; ++jt) {
        #pragma unroll
        for (int r = 0; r < 4; ++r) {
            float v = acc[jt][r];
            v = v > 0.f ? v : 0.01f * v;
            hw[(q * 4 + r) * 68 + jt * 16 + p] = v;
        }
    }
    // ---- L2: A from hw (pack f32->bf16), B direct from W2b ----
    bf16x8 a2f[2];
    #pragma unroll
    for (int kc = 0; kc < 2; ++kc) {
        const float* hp = hw + p * 68 + kc * 32 + q * 8;
        f32x4 v0 = *(const f32x4*)hp;
        f32x4 v1 = *(const f32x4*)(hp + 4);
        uint4 uu = make_uint4(pk2(v0[0], v0[1]), pk2(v0[2], v0[3]),
                              pk2(v1[0], v1[1]), pk2(v1[2], v1[3]));
        a2f[kc] = *(const bf16x8*)&uu;
    }
    f32x4 acc2[2];
    #pragma unroll
    for (int jt = 0; jt < 2; ++jt) {
        float bv = b2[jt * 16 + p];
        acc2[jt][0] = bv; acc2[jt][1] = bv; acc2[jt][2] = bv; acc2[jt][3] = bv;
        #pragma unroll
        for (int kc = 0; kc < 2; ++kc) {
            uint4 u = *(const uint4*)(W2b + (jt * 16 + p) * 32 + kc * 16 + q * 4);
            bf16x8 bf = *(const bf16x8*)&u;
            acc2[jt] = __builtin_amdgcn_mfma_f32_16x16x32_bf16(a2f[kc], bf, acc2[jt], 0, 0, 0);
        }
    }
    // h2 -> same wave-private LDS (all h1 reads by this wave precede, in-order LDS)
    #pragma unroll
    for (int jt = 0; jt < 2; ++jt) {
        #pragma unroll
        for (int r = 0; r < 4; ++r) {
            float v = acc2[jt][r];
            v = v > 0.f ? v : 0.01f * v;
            hw[(q * 4 + r) * 36 + jt * 16 + p] = v;
        }
    }
    // ---- L3+L4 scalar tail (q-groups redundant; W3/W4 via s_load) ----
    float a3[21];
    #pragma unroll
    for (int j = 0; j < 21; ++j) a3[j] = b3[j];
    #pragma unroll 4
    for (int k = 0; k < 32; ++k) {
        float hk = hw[p * 36 + k];
        fma21(hk, W3 + k * 21, a3);
    }
    float s = 0.f;
    #pragma unroll
    for (int j = 0; j < 21; ++j) {
        float vj = a3[j] > 0.f ? a3[j] : 0.01f * a3[j];
        s = fmaf(vj, W4[j], s);
    }
    if (q == 0) {
        if (node < NN) out[node] = 1.f / (1.f + expf(-s));
    }
}

extern "C" void kernel_launch(void* const* d_in, const int* in_sizes, int n_in,
                              void* d_out, int out_size, void* d_ws, size_t ws_size,
                              hipStream_t stream) {
    const float* feat = (const float*)d_in[0];
    const int*   index = (const int*)d_in[1];
    const int*   erow = (const int*)d_in[2];
    const int*   ecol = (const int*)d_in[3];
    const float* evalp = (const float*)d_in[4];
    const float* W1 = (const float*)d_in[5];
    const float* b1 = (const float*)d_in[6];
    const float* W2 = (const float*)d_in[7];
    const float* b2 = (const float*)d_in[8];
    const float* W3 = (const float*)d_in[9];
    const float* b3 = (const float*)d_in[10];
    const float* W4 = (const float*)d_in[11];
    float* out = (float*)d_out;

    char* ws = (char*)d_ws;
    size_t off = 0;
    auto alloc = [&](size_t bytes) -> void* {
        void* p = ws + off;
        off += (bytes + 255) & ~(size_t)255;
        return p;
    };
    // dcpack + invidx1 contiguous: ONE zeroing memset covers both
    unsigned long long* dcpack = (unsigned long long*)alloc((size_t)MM * 8);
    int*   invidx1 = (int*)  alloc((size_t)NN * 4);
    size_t zero_span = (size_t)((char*)invidx1 - (char*)dcpack) + (size_t)NN * 4;

    int2*  cv_s    = (int2*) alloc((size_t)EE4 * 8);
    float* dis     = (float*)alloc((size_t)MM * 4);
    int*   cnt     = (int*)  alloc((size_t)MM * 4);
    int*   slot    = (int*)  alloc((size_t)EE * 4);
    int*   row_s4  = (int*)  alloc((size_t)MM * 4);
    int*   blockhist = (int*)alloc((size_t)256 * NB * 4);
    int*   blockoff  = (int*)alloc((size_t)256 * NB * 4);
    int*   total     = (int*)alloc((size_t)256 * 4);
    int4*  meta      = (int4*)alloc((size_t)MM * 16);
    unsigned* W1b  = (unsigned*)alloc(4096 * 4);
    unsigned* W2b  = (unsigned*)alloc(1024 * 4);
    unsigned* X0   = (unsigned*)alloc((size_t)MM * DD * 2);  // row-major [MM][64 dwords]
    unsigned* Xa   = (unsigned*)alloc((size_t)MM * DD * 2);
    unsigned* Xb   = (unsigned*)alloc((size_t)MM * DD * 2);
    unsigned* Xc   = (unsigned*)alloc((size_t)MM * DD * 2);

    (void)hipMemsetAsync(dcpack, 0, zero_span, stream);

    front_kernel<<<(MM * 32) / 256, 256, 0, stream>>>(
        erow, evalp, dcpack, slot, feat, index, invidx1, X0, W1, W2, W1b, W2b);
    setup_kernel<<<NB, 256, 0, stream>>>(dcpack, dis, cnt, blockhist);
    scan_kernel<<<256, 64, 0, stream>>>(blockhist, blockoff, total);
    sort_kernel<<<NB, 256, 0, stream>>>(cnt, blockoff, total, meta, row_s4, cv_s);
    scatter_kernel<<<(EE + 255) / 256, 256, 0, stream>>>(erow, ecol, evalp, dis,
                                                         row_s4, slot, cv_s);

    spmm_kernel<<<SPGRID, 256, 0, stream>>>(meta, cv_s,
                                            (const unsigned short*)X0, (unsigned short*)Xa);
    spmm_kernel<<<SPGRID, 256, 0, stream>>>(meta, cv_s,
                                            (const unsigned short*)Xa, (unsigned short*)Xb);
    spmm_kernel<<<SPGRID, 256, 0, stream>>>(meta, cv_s,
                                            (const unsigned short*)Xb, (unsigned short*)Xc);

    mlp_kernel<<<(NNP + 63) / 64, 256, 0, stream>>>(Xc, feat, invidx1,
                                                    W1b, b1, W2b, b2,
                                                    W3, b3, W4, out);
}